// Round 2
// baseline (57.592 us; speedup 1.0000x reference)
//
#include <hip/hip_runtime.h>
#include <stdint.h>

typedef __attribute__((ext_vector_type(8))) short short8;
typedef __attribute__((ext_vector_type(4))) float f32x4;

#define DEVI __device__ __forceinline__

DEVI ushort f2bf(float f) {
  union { float f; uint32_t u; } v; v.f = f;
  uint32_t r = v.u + 0x7fffu + ((v.u >> 16) & 1u);
  return (ushort)(r >> 16);
}
DEVI float bf2f(ushort h) {
  union { uint32_t u; float f; } v; v.u = ((uint32_t)h) << 16;
  return v.f;
}

// ---------------------------------------------------------------------------
// Quantum sim collapses analytically:
//  - RZ phases are diagonal -> cancel in |amp|^2 -> params input is DEAD.
//  - two CNOT chains = linear bit map: z0=x0, z1=x1, z2=x0^x2, z3=x1^x3
//  - product state => E[Z_i] factorizes:
//    f = [cos v0, cos v1, cos v0*cos v2, cos v1*cos v3] per 2x2 patch.
// feats written bf16, padded 784 -> 832 cols (zeros) for BK=64 GEMM.
// ---------------------------------------------------------------------------
__global__ __launch_bounds__(256) void feats_kernel(const float* __restrict__ x,
                                                    ushort* __restrict__ feats) {
  int t = blockIdx.x * 256 + threadIdx.x;   // 8192 * 208 items
  int row = t / 208;
  int q = t - row * 208;
  if (q < 196) {
    int i = q / 14, j = q - i * 14;
    const float* px = x + (size_t)row * 784 + i * 56 + j * 2;
    float2 top = *(const float2*)px;
    float2 bot = *(const float2*)(px + 28);
    float c0 = __cosf(top.x), c1 = __cosf(top.y);
    float c2 = __cosf(bot.x), c3 = __cosf(bot.y);
    ushort4 o;
    o.x = f2bf(c0); o.y = f2bf(c1); o.z = f2bf(c0 * c2); o.w = f2bf(c1 * c3);
    *(ushort4*)(feats + (size_t)row * 832 + q * 4) = o;
  } else {
    ushort4 z; z.x = 0; z.y = 0; z.z = 0; z.w = 0;
    *(ushort4*)(feats + (size_t)row * 832 + 784 + (q - 196) * 4) = z;
  }
}

// Cast W1 (pad 784->832 with zeros) and W2 to bf16.
__global__ __launch_bounds__(256) void prep_kernel(const float* __restrict__ W1,
                                                   const float* __restrict__ W2,
                                                   ushort* __restrict__ w1b,
                                                   ushort* __restrict__ w2b) {
  int t = blockIdx.x * 256 + threadIdx.x;   // 256*832 + 128*256 = 245760
  if (t < 256 * 832) {
    int r = t / 832, c = t - r * 832;
    w1b[t] = (c < 784) ? f2bf(W1[r * 784 + c]) : (ushort)0;
  } else {
    int u = t - 256 * 832;
    w2b[u] = f2bf(W2[u]);
  }
}

// ---------------------------------------------------------------------------
// C[M][N] = relu?(A[M][K] @ W[N][K]^T + bias), bf16 in / bf16 out, fp32 acc.
// 256 threads = 4 waves in 2x2; wave tile (BM/2)x(BN/2); 16x16x32 bf16 MFMA.
// Reg-staged LDS, +8 ushort pad per row (144B stride -> conflict-free b128).
// ---------------------------------------------------------------------------
template <int BM, int BN, int BK, bool RELU>
__global__ __launch_bounds__(256) void gemm_bt(const ushort* __restrict__ A,
                                               const ushort* __restrict__ W,
                                               const float* __restrict__ bias,
                                               ushort* __restrict__ C,
                                               int M, int N, int K) {
  constexpr int MF = BM / 32;       // M fragments per wave
  constexpr int NF = BN / 32;       // N fragments per wave
  constexpr int LDA = BK + 8;       // padded LDS row stride (ushorts)
  constexpr int SLOTS = BK / 8;     // 16B slots per row
  constexpr int A_IT = BM * SLOTS / 256;
  constexpr int B_IT = BN * SLOTS / 256;

  __shared__ ushort As[BM * LDA];
  __shared__ ushort Bs[BN * LDA];

  const int mtiles = M / BM;
  const int bm = blockIdx.x % mtiles;
  const int bn = blockIdx.x / mtiles;
  const int m0 = bm * BM, n0 = bn * BN;

  const int tid = threadIdx.x;
  const int lane = tid & 63;
  const int w = tid >> 6;
  const int wm = w >> 1, wn = w & 1;

  f32x4 acc[MF][NF];
#pragma unroll
  for (int m = 0; m < MF; ++m)
#pragma unroll
    for (int n = 0; n < NF; ++n) {
      f32x4 z = {0.f, 0.f, 0.f, 0.f};
      acc[m][n] = z;
    }

  const int nk = K / BK;
  for (int kt = 0; kt < nk; ++kt) {
    const int k0 = kt * BK;
    uint4 av[A_IT], bv[B_IT];
#pragma unroll
    for (int c = 0; c < A_IT; ++c) {
      int flat = c * 256 + tid;
      int r = flat / SLOTS, s = flat % SLOTS;
      av[c] = *(const uint4*)(A + (size_t)(m0 + r) * K + k0 + s * 8);
    }
#pragma unroll
    for (int c = 0; c < B_IT; ++c) {
      int flat = c * 256 + tid;
      int r = flat / SLOTS, s = flat % SLOTS;
      bv[c] = *(const uint4*)(W + (size_t)(n0 + r) * K + k0 + s * 8);
    }
#pragma unroll
    for (int c = 0; c < A_IT; ++c) {
      int flat = c * 256 + tid;
      int r = flat / SLOTS, s = flat % SLOTS;
      *(uint4*)(As + r * LDA + s * 8) = av[c];
    }
#pragma unroll
    for (int c = 0; c < B_IT; ++c) {
      int flat = c * 256 + tid;
      int r = flat / SLOTS, s = flat % SLOTS;
      *(uint4*)(Bs + r * LDA + s * 8) = bv[c];
    }
    __syncthreads();

#pragma unroll
    for (int ks = 0; ks < BK / 32; ++ks) {
      short8 af[MF], bfr[NF];
#pragma unroll
      for (int m = 0; m < MF; ++m) {
        int r = wm * (BM / 2) + m * 16 + (lane & 15);
        af[m] = *(const short8*)(As + r * LDA + ks * 32 + (lane >> 4) * 8);
      }
#pragma unroll
      for (int n = 0; n < NF; ++n) {
        int cidx = wn * (BN / 2) + n * 16 + (lane & 15);
        bfr[n] = *(const short8*)(Bs + cidx * LDA + ks * 32 + (lane >> 4) * 8);
      }
#pragma unroll
      for (int m = 0; m < MF; ++m)
#pragma unroll
        for (int n = 0; n < NF; ++n)
          acc[m][n] = __builtin_amdgcn_mfma_f32_16x16x32_bf16(af[m], bfr[n], acc[m][n], 0, 0, 0);
    }
    __syncthreads();
  }

  // epilogue: C/D layout col = lane&15, row = (lane>>4)*4 + reg   [m89-verified]
#pragma unroll
  for (int m = 0; m < MF; ++m) {
#pragma unroll
    for (int n = 0; n < NF; ++n) {
      int colg = n0 + wn * (BN / 2) + n * 16 + (lane & 15);
      float bval = bias[colg];
#pragma unroll
      for (int r = 0; r < 4; ++r) {
        int rowg = m0 + wm * (BM / 2) + m * 16 + (lane >> 4) * 4 + r;
        float v = acc[m][n][r] + bval;
        if (RELU) v = fmaxf(v, 0.f);
        C[(size_t)rowg * N + colg] = f2bf(v);
      }
    }
  }
}

// ---------------------------------------------------------------------------
// logits = h2 @ W3^T + b3 ; log_softmax. One thread per batch row.
// W3/b3 indices are wave-uniform -> scalar loads.
// ---------------------------------------------------------------------------
__global__ __launch_bounds__(256) void head_kernel(const ushort* __restrict__ h2,
                                                   const float* __restrict__ W3,
                                                   const float* __restrict__ b3,
                                                   float* __restrict__ out) {
  int row = blockIdx.x * 256 + threadIdx.x;   // 8192 rows
  float acc[10];
#pragma unroll
  for (int n = 0; n < 10; ++n) acc[n] = b3[n];
  const ushort* hr = h2 + (size_t)row * 128;
#pragma unroll
  for (int kc = 0; kc < 16; ++kc) {
    uint4 qv = *(const uint4*)(hr + kc * 8);
    float hv[8];
    hv[0] = bf2f((ushort)(qv.x & 0xffff)); hv[1] = bf2f((ushort)(qv.x >> 16));
    hv[2] = bf2f((ushort)(qv.y & 0xffff)); hv[3] = bf2f((ushort)(qv.y >> 16));
    hv[4] = bf2f((ushort)(qv.z & 0xffff)); hv[5] = bf2f((ushort)(qv.z >> 16));
    hv[6] = bf2f((ushort)(qv.w & 0xffff)); hv[7] = bf2f((ushort)(qv.w >> 16));
#pragma unroll
    for (int n = 0; n < 10; ++n) {
#pragma unroll
      for (int e = 0; e < 8; ++e)
        acc[n] = fmaf(hv[e], W3[n * 128 + kc * 8 + e], acc[n]);
    }
  }
  float mx = acc[0];
#pragma unroll
  for (int n = 1; n < 10; ++n) mx = fmaxf(mx, acc[n]);
  float s = 0.f;
#pragma unroll
  for (int n = 0; n < 10; ++n) s += __expf(acc[n] - mx);
  float lse = mx + __logf(s);
#pragma unroll
  for (int n = 0; n < 10; ++n) out[(size_t)row * 10 + n] = acc[n] - lse;
}

// ---------------------------------------------------------------------------
extern "C" void kernel_launch(void* const* d_in, const int* in_sizes, int n_in,
                              void* d_out, int out_size, void* d_ws, size_t ws_size,
                              hipStream_t stream) {
  const float* x  = (const float*)d_in[0];   // (8192,1,28,28)
  // d_in[1] = params (2,4): provably unused (diagonal phases cancel in |amp|^2)
  const float* W1 = (const float*)d_in[2];
  const float* b1 = (const float*)d_in[3];
  const float* W2 = (const float*)d_in[4];
  const float* b2 = (const float*)d_in[5];
  const float* W3 = (const float*)d_in[6];
  const float* b3 = (const float*)d_in[7];
  float* out = (float*)d_out;

  // workspace layout (needs ~20.5 MB)
  char* ws = (char*)d_ws;
  ushort* feats = (ushort*)(ws);                      // 8192 x 832 bf16
  ushort* w1b   = (ushort*)(ws + 13631488);           // 256 x 832 bf16
  ushort* h1    = (ushort*)(ws + 14057472);           // 8192 x 256 bf16
  ushort* w2b   = (ushort*)(ws + 18251776);           // 128 x 256 bf16
  ushort* h2    = (ushort*)(ws + 18317312);           // 8192 x 128 bf16

  hipLaunchKernelGGL(prep_kernel, dim3(960), dim3(256), 0, stream, W1, W2, w1b, w2b);
  hipLaunchKernelGGL(feats_kernel, dim3(8192 * 208 / 256), dim3(256), 0, stream, x, feats);
  hipLaunchKernelGGL((gemm_bt<128, 64, 64, true>), dim3((8192 / 128) * (256 / 64)), dim3(256), 0,
                     stream, feats, w1b, b1, h1, 8192, 256, 832);
  hipLaunchKernelGGL((gemm_bt<64, 64, 64, true>), dim3((8192 / 64) * (128 / 64)), dim3(256), 0,
                     stream, h1, w2b, b2, h2, 8192, 128, 256);
  hipLaunchKernelGGL(head_kernel, dim3(8192 / 256), dim3(256), 0, stream, h2, W3, b3, out);
}

// Round 3
// 47.470 us; speedup vs baseline: 1.2132x; 1.2132x over previous
//
#include <hip/hip_runtime.h>
#include <stdint.h>

typedef __attribute__((ext_vector_type(8))) short short8;
typedef __attribute__((ext_vector_type(4))) float f32x4;

#define DEVI __device__ __forceinline__

DEVI ushort f2bf(float f) {
  union { float f; uint32_t u; } v; v.f = f;
  uint32_t r = v.u + 0x7fffu + ((v.u >> 16) & 1u);
  return (ushort)(r >> 16);
}
DEVI float bf2f(ushort h) {
  union { uint32_t u; float f; } v; v.u = ((uint32_t)h) << 16;
  return v.f;
}

// ---------------------------------------------------------------------------
// Quantum sim collapses analytically (params provably dead):
//   f = [cos v0, cos v1, cos v0*cos v2, cos v1*cos v3] per 2x2 patch.
// Fused: blocks [0,6656) compute feats (bf16, padded 784->832),
//        blocks [6656,7616) cast W1 (pad->832) and W2 to bf16.
// ---------------------------------------------------------------------------
__global__ __launch_bounds__(256) void feats_prep_kernel(
    const float* __restrict__ x, ushort* __restrict__ feats,
    const float* __restrict__ W1, const float* __restrict__ W2,
    ushort* __restrict__ w1b, ushort* __restrict__ w2b) {
  int b = blockIdx.x;
  if (b < 6656) {
    int t = b * 256 + threadIdx.x;   // 8192 * 208 items
    int row = t / 208;
    int q = t - row * 208;
    if (q < 196) {
      int i = q / 14, j = q - i * 14;
      const float* px = x + (size_t)row * 784 + i * 56 + j * 2;
      float2 top = *(const float2*)px;
      float2 bot = *(const float2*)(px + 28);
      float c0 = __cosf(top.x), c1 = __cosf(top.y);
      float c2 = __cosf(bot.x), c3 = __cosf(bot.y);
      ushort4 o;
      o.x = f2bf(c0); o.y = f2bf(c1); o.z = f2bf(c0 * c2); o.w = f2bf(c1 * c3);
      *(ushort4*)(feats + (size_t)row * 832 + q * 4) = o;
    } else {
      ushort4 z; z.x = 0; z.y = 0; z.z = 0; z.w = 0;
      *(ushort4*)(feats + (size_t)row * 832 + 784 + (q - 196) * 4) = z;
    }
  } else {
    int t = (b - 6656) * 256 + threadIdx.x;   // 256*832 + 128*256 = 245760
    if (t < 256 * 832) {
      int r = t / 832, c = t - r * 832;
      w1b[t] = (c < 784) ? f2bf(W1[r * 784 + c]) : (ushort)0;
    } else {
      int u = t - 256 * 832;
      w2b[u] = f2bf(W2[u]);
    }
  }
}

// ---------------------------------------------------------------------------
// GEMM1: h1 = relu(feats @ W1^T + b1). BM=64 -> 512 blocks = 2 blocks/CU so
// one block's MFMA hides the other's global-load/barrier stall.
// ---------------------------------------------------------------------------
template <int BM, int BN, int BK, bool RELU>
__global__ __launch_bounds__(256) void gemm_bt(const ushort* __restrict__ A,
                                               const ushort* __restrict__ W,
                                               const float* __restrict__ bias,
                                               ushort* __restrict__ C,
                                               int M, int N, int K) {
  constexpr int MF = BM / 32;
  constexpr int NF = BN / 32;
  constexpr int LDA = BK + 8;       // padded LDS row stride (ushorts)
  constexpr int SLOTS = BK / 8;
  constexpr int A_IT = BM * SLOTS / 256;
  constexpr int B_IT = BN * SLOTS / 256;

  __shared__ ushort As[BM * LDA];
  __shared__ ushort Bs[BN * LDA];

  const int mtiles = M / BM;
  const int bm = blockIdx.x % mtiles;
  const int bn = blockIdx.x / mtiles;
  const int m0 = bm * BM, n0 = bn * BN;

  const int tid = threadIdx.x;
  const int lane = tid & 63;
  const int w = tid >> 6;
  const int wm = w >> 1, wn = w & 1;

  f32x4 acc[MF][NF];
#pragma unroll
  for (int m = 0; m < MF; ++m)
#pragma unroll
    for (int n = 0; n < NF; ++n) {
      f32x4 z = {0.f, 0.f, 0.f, 0.f};
      acc[m][n] = z;
    }

  const int nk = K / BK;
  for (int kt = 0; kt < nk; ++kt) {
    const int k0 = kt * BK;
    uint4 av[A_IT], bv[B_IT];
#pragma unroll
    for (int c = 0; c < A_IT; ++c) {
      int flat = c * 256 + tid;
      int r = flat / SLOTS, s = flat % SLOTS;
      av[c] = *(const uint4*)(A + (size_t)(m0 + r) * K + k0 + s * 8);
    }
#pragma unroll
    for (int c = 0; c < B_IT; ++c) {
      int flat = c * 256 + tid;
      int r = flat / SLOTS, s = flat % SLOTS;
      bv[c] = *(const uint4*)(W + (size_t)(n0 + r) * K + k0 + s * 8);
    }
#pragma unroll
    for (int c = 0; c < A_IT; ++c) {
      int flat = c * 256 + tid;
      int r = flat / SLOTS, s = flat % SLOTS;
      *(uint4*)(As + r * LDA + s * 8) = av[c];
    }
#pragma unroll
    for (int c = 0; c < B_IT; ++c) {
      int flat = c * 256 + tid;
      int r = flat / SLOTS, s = flat % SLOTS;
      *(uint4*)(Bs + r * LDA + s * 8) = bv[c];
    }
    __syncthreads();

#pragma unroll
    for (int ks = 0; ks < BK / 32; ++ks) {
      short8 af[MF], bfr[NF];
#pragma unroll
      for (int m = 0; m < MF; ++m) {
        int r = wm * (BM / 2) + m * 16 + (lane & 15);
        af[m] = *(const short8*)(As + r * LDA + ks * 32 + (lane >> 4) * 8);
      }
#pragma unroll
      for (int n = 0; n < NF; ++n) {
        int cidx = wn * (BN / 2) + n * 16 + (lane & 15);
        bfr[n] = *(const short8*)(Bs + cidx * LDA + ks * 32 + (lane >> 4) * 8);
      }
#pragma unroll
      for (int m = 0; m < MF; ++m)
#pragma unroll
        for (int n = 0; n < NF; ++n)
          acc[m][n] = __builtin_amdgcn_mfma_f32_16x16x32_bf16(af[m], bfr[n], acc[m][n], 0, 0, 0);
    }
    __syncthreads();
  }

  // C/D layout: col = lane&15, row = (lane>>4)*4 + reg   [m89-verified]
#pragma unroll
  for (int m = 0; m < MF; ++m) {
#pragma unroll
    for (int n = 0; n < NF; ++n) {
      int colg = n0 + wn * (BN / 2) + n * 16 + (lane & 15);
      float bval = bias[colg];
#pragma unroll
      for (int r = 0; r < 4; ++r) {
        int rowg = m0 + wm * (BM / 2) + m * 16 + (lane >> 4) * 4 + r;
        float v = acc[m][n][r] + bval;
        if (RELU) v = fmaxf(v, 0.f);
        C[(size_t)rowg * N + colg] = f2bf(v);
      }
    }
  }
}

// ---------------------------------------------------------------------------
// Fused GEMM2 + head: h2 = relu(h1 @ W2^T + b2) stays in LDS; then
// logits = h2 @ W3^T + b3 and log_softmax, all in one block.
// BM=32, BN=128 (full N) -> 256 blocks. Head mapping k = e*8+p keeps
// W3s reads broadcast/conflict-free; reduce over p via shfl_xor.
// ---------------------------------------------------------------------------
__global__ __launch_bounds__(256) void gemm2_head_kernel(
    const ushort* __restrict__ A,      // h1: 8192 x 256 bf16
    const ushort* __restrict__ W,      // w2b: 128 x 256 bf16
    const float* __restrict__ b2,
    const float* __restrict__ W3,      // 10 x 128 f32
    const float* __restrict__ b3,
    float* __restrict__ out) {
  constexpr int BM = 32, BN = 128, BK = 64, K = 256;
  constexpr int LDA = BK + 8;
  constexpr int NF = 4;               // wave tile 16 x 64

  __shared__ ushort As[BM * LDA];
  __shared__ ushort Bs[BN * LDA];
  __shared__ float h2f[BM][132];
  __shared__ float W3s[1280];

  const int tid = threadIdx.x;
  const int lane = tid & 63;
  const int w = tid >> 6;
  const int wm = w >> 1, wn = w & 1;
  const int m0 = blockIdx.x * BM;

  for (int i = tid; i < 1280; i += 256) W3s[i] = W3[i];

  f32x4 acc[NF];
#pragma unroll
  for (int n = 0; n < NF; ++n) {
    f32x4 z = {0.f, 0.f, 0.f, 0.f};
    acc[n] = z;
  }

#pragma unroll
  for (int kt = 0; kt < K / BK; ++kt) {
    const int k0 = kt * BK;
    // A: 32 rows x 8 slots = 256 items (1 per thread)
    {
      int r = tid >> 3, s = tid & 7;
      uint4 av = *(const uint4*)(A + (size_t)(m0 + r) * K + k0 + s * 8);
      uint4 bv[4];
#pragma unroll
      for (int c = 0; c < 4; ++c) {
        int flat = c * 256 + tid;
        int rb = flat >> 3, sb = flat & 7;
        bv[c] = *(const uint4*)(W + (size_t)rb * K + k0 + sb * 8);
      }
      *(uint4*)(As + r * LDA + s * 8) = av;
#pragma unroll
      for (int c = 0; c < 4; ++c) {
        int flat = c * 256 + tid;
        int rb = flat >> 3, sb = flat & 7;
        *(uint4*)(Bs + rb * LDA + sb * 8) = bv[c];
      }
    }
    __syncthreads();
#pragma unroll
    for (int ks = 0; ks < BK / 32; ++ks) {
      int r = wm * 16 + (lane & 15);
      short8 af = *(const short8*)(As + r * LDA + ks * 32 + (lane >> 4) * 8);
#pragma unroll
      for (int n = 0; n < NF; ++n) {
        int cidx = wn * 64 + n * 16 + (lane & 15);
        short8 bfr = *(const short8*)(Bs + cidx * LDA + ks * 32 + (lane >> 4) * 8);
        acc[n] = __builtin_amdgcn_mfma_f32_16x16x32_bf16(af, bfr, acc[n], 0, 0, 0);
      }
    }
    __syncthreads();
  }

  // h2 tile -> LDS (relu + bias)
#pragma unroll
  for (int n = 0; n < NF; ++n) {
    int col = wn * 64 + n * 16 + (lane & 15);
    float bval = b2[col];
#pragma unroll
    for (int r = 0; r < 4; ++r) {
      int rowl = wm * 16 + (lane >> 4) * 4 + r;
      h2f[rowl][col] = fmaxf(acc[n][r] + bval, 0.f);
    }
  }
  __syncthreads();

  // head: row r = tid>>3 (32 rows), partial p = tid&7 over k = e*8+p
  {
    int r = tid >> 3, p = tid & 7;
    float a10[10];
#pragma unroll
    for (int n = 0; n < 10; ++n) a10[n] = 0.f;
#pragma unroll
    for (int e = 0; e < 16; ++e) {
      int k = e * 8 + p;
      float hv = h2f[r][k];
#pragma unroll
      for (int n = 0; n < 10; ++n) a10[n] = fmaf(hv, W3s[n * 128 + k], a10[n]);
    }
#pragma unroll
    for (int n = 0; n < 10; ++n) {
      a10[n] += __shfl_xor(a10[n], 1);
      a10[n] += __shfl_xor(a10[n], 2);
      a10[n] += __shfl_xor(a10[n], 4);
    }
    if (p == 0) {
#pragma unroll
      for (int n = 0; n < 10; ++n) a10[n] += b3[n];
      float mx = a10[0];
#pragma unroll
      for (int n = 1; n < 10; ++n) mx = fmaxf(mx, a10[n]);
      float s = 0.f;
#pragma unroll
      for (int n = 0; n < 10; ++n) s += __expf(a10[n] - mx);
      float lse = mx + __logf(s);
      float* po = out + (size_t)(m0 + r) * 10;
#pragma unroll
      for (int n = 0; n < 10; ++n) po[n] = a10[n] - lse;
    }
  }
}

// ---------------------------------------------------------------------------
extern "C" void kernel_launch(void* const* d_in, const int* in_sizes, int n_in,
                              void* d_out, int out_size, void* d_ws, size_t ws_size,
                              hipStream_t stream) {
  const float* x  = (const float*)d_in[0];   // (8192,1,28,28)
  // d_in[1] = params: provably unused (diagonal phases cancel in |amp|^2)
  const float* W1 = (const float*)d_in[2];
  const float* b1 = (const float*)d_in[3];
  const float* W2 = (const float*)d_in[4];
  const float* b2 = (const float*)d_in[5];
  const float* W3 = (const float*)d_in[6];
  const float* b3 = (const float*)d_in[7];
  float* out = (float*)d_out;

  char* ws = (char*)d_ws;
  ushort* feats = (ushort*)(ws);                      // 8192 x 832 bf16
  ushort* w1b   = (ushort*)(ws + 13631488);           // 256 x 832 bf16
  ushort* h1    = (ushort*)(ws + 14057472);           // 8192 x 256 bf16
  ushort* w2b   = (ushort*)(ws + 18251776);           // 128 x 256 bf16

  hipLaunchKernelGGL(feats_prep_kernel, dim3(7616), dim3(256), 0, stream,
                     x, feats, W1, W2, w1b, w2b);
  hipLaunchKernelGGL((gemm_bt<64, 64, 64, true>), dim3((8192 / 64) * (256 / 64)), dim3(256), 0,
                     stream, feats, w1b, b1, h1, 8192, 256, 832);
  hipLaunchKernelGGL(gemm2_head_kernel, dim3(8192 / 32), dim3(256), 0, stream,
                     h1, w2b, b2, W3, b3, out);
}

// Round 4
// 30.879 us; speedup vs baseline: 1.8651x; 1.5373x over previous
//
#include <hip/hip_runtime.h>
#include <stdint.h>

typedef __attribute__((ext_vector_type(8))) short short8;
typedef __attribute__((ext_vector_type(4))) float f32x4;

#define DEVI __device__ __forceinline__

DEVI ushort f2bf(float f) {
  union { float f; uint32_t u; } v; v.f = f;
  uint32_t r = v.u + 0x7fffu + ((v.u >> 16) & 1u);
  return (ushort)(r >> 16);
}

DEVI ushort4 pack4(float a, float b, float c, float d) {
  ushort4 o; o.x = f2bf(a); o.y = f2bf(b); o.z = f2bf(c); o.w = f2bf(d);
  return o;
}

// ---------------------------------------------------------------------------
// Quantum sim collapses analytically (params provably dead):
//   feats per 2x2 patch (v0,v1,v2,v3) = [cos v0, cos v1, cos v0*cos v2,
//   cos v1*cos v3];  two CNOT chains = linear map z0=x0,z1=x1,z2=x0^x2,
//   z3=x1^x3; RZ phases cancel in |amp|^2.
//
// Kernel 1: h1 = relu(feats(x) @ W1b^T + b1), feats computed on the fly into
// LDS (no feats array, no prep kernel), W1 cast f32->bf16 during staging.
// BM=BN=64, BK=64, 512 blocks = 2 blocks/CU; double-buffered LDS so the
// global-load latency hides under MFMA + cos VALU of the co-resident block.
// K = 832 (208 patch-cols, 196 real + 12 zero pad).
// ---------------------------------------------------------------------------
__global__ __launch_bounds__(256) void gemm1_fused(
    const float* __restrict__ x, const float* __restrict__ W1,
    const float* __restrict__ b1, ushort* __restrict__ h1) {
  constexpr int LDA = 72;   // 144B row stride: 4r%32 banks -> <=2-way (free)
  constexpr int NK = 13;    // K = 832
  __shared__ ushort As[2][64 * LDA];
  __shared__ ushort Bs[2][64 * LDA];

  const int tid = threadIdx.x;
  const int lane = tid & 63;
  const int w = tid >> 6, wm = w >> 1, wn = w & 1;
  const int bm = blockIdx.x & 127, bn = blockIdx.x >> 7;
  const int m0 = bm * 64, n0 = bn * 64;

  const int srow = tid >> 4;        // 0..15: sub-row in each 16-row group
  const int pl = tid & 15;          // patch slot within k-tile
  const int kc4 = pl * 4;           // B k-offset

  float2 atop[4], abot[4];          // staged x values (4 rows, 1 patch)
  float4 bw[4];                     // staged W1 values (4 rows, 4 cols)

  f32x4 acc[2][2];
#pragma unroll
  for (int m = 0; m < 2; ++m)
#pragma unroll
    for (int n = 0; n < 2; ++n) {
      f32x4 z = {0.f, 0.f, 0.f, 0.f};
      acc[m][n] = z;
    }

  auto loadT = [&](int kt) {
    const int q = kt * 16 + pl;                 // patch index (same for all c)
    if (q < 196) {
      const int i = q / 14, j = q - i * 14;
      const float* px = x + i * 56 + j * 2;
#pragma unroll
      for (int c = 0; c < 4; ++c) {
        const float* p = px + (size_t)(m0 + c * 16 + srow) * 784;
        atop[c] = *(const float2*)p;
        abot[c] = *(const float2*)(p + 28);
      }
    }
    const int k0 = kt * 64;
    if (k0 + kc4 < 784) {
#pragma unroll
      for (int c = 0; c < 4; ++c)
        bw[c] = *(const float4*)(W1 + (size_t)(n0 + c * 16 + srow) * 784 + k0 + kc4);
    } else {
#pragma unroll
      for (int c = 0; c < 4; ++c) bw[c] = make_float4(0.f, 0.f, 0.f, 0.f);
    }
  };

  auto writeT = [&](int buf, int kt) {
    const int q = kt * 16 + pl;
    ushort* as = As[buf];
    ushort* bs = Bs[buf];
    if (q < 196) {
#pragma unroll
      for (int c = 0; c < 4; ++c) {
        float c0 = __cosf(atop[c].x), c1 = __cosf(atop[c].y);
        float c2 = __cosf(abot[c].x), c3 = __cosf(abot[c].y);
        *(ushort4*)(as + (c * 16 + srow) * LDA + pl * 4) =
            pack4(c0, c1, c0 * c2, c1 * c3);
      }
    } else {
      ushort4 z; z.x = 0; z.y = 0; z.z = 0; z.w = 0;
#pragma unroll
      for (int c = 0; c < 4; ++c)
        *(ushort4*)(as + (c * 16 + srow) * LDA + pl * 4) = z;
    }
#pragma unroll
    for (int c = 0; c < 4; ++c)
      *(ushort4*)(bs + (c * 16 + srow) * LDA + kc4) =
          pack4(bw[c].x, bw[c].y, bw[c].z, bw[c].w);
  };

  auto mma = [&](int buf) {
    const ushort* as = As[buf];
    const ushort* bs = Bs[buf];
#pragma unroll
    for (int ks = 0; ks < 2; ++ks) {
      short8 af[2], bf[2];
#pragma unroll
      for (int m = 0; m < 2; ++m) {
        int r = wm * 32 + m * 16 + (lane & 15);
        af[m] = *(const short8*)(as + r * LDA + ks * 32 + (lane >> 4) * 8);
      }
#pragma unroll
      for (int n = 0; n < 2; ++n) {
        int cdx = wn * 32 + n * 16 + (lane & 15);
        bf[n] = *(const short8*)(bs + cdx * LDA + ks * 32 + (lane >> 4) * 8);
      }
#pragma unroll
      for (int m = 0; m < 2; ++m)
#pragma unroll
        for (int n = 0; n < 2; ++n)
          acc[m][n] = __builtin_amdgcn_mfma_f32_16x16x32_bf16(af[m], bf[n], acc[m][n], 0, 0, 0);
    }
  };

  // double-buffered pipeline: 1 barrier per K-step, next tile's global loads
  // issued before current tile's MFMA.
  loadT(0);
  writeT(0, 0);
  __syncthreads();
  int cur = 0;
  for (int kt = 0; kt < NK; ++kt) {
    if (kt + 1 < NK) loadT(kt + 1);
    mma(cur);
    if (kt + 1 < NK) writeT(cur ^ 1, kt + 1);
    __syncthreads();
    cur ^= 1;
  }

  // C/D layout: col = lane&15, row = (lane>>4)*4 + reg   [m89-verified]
#pragma unroll
  for (int m = 0; m < 2; ++m)
#pragma unroll
    for (int n = 0; n < 2; ++n) {
      int colg = n0 + wn * 32 + n * 16 + (lane & 15);
      float bval = b1[colg];
#pragma unroll
      for (int r = 0; r < 4; ++r) {
        int rowg = m0 + wm * 32 + m * 16 + (lane >> 4) * 4 + r;
        h1[(size_t)rowg * 256 + colg] = f2bf(fmaxf(acc[m][n][r] + bval, 0.f));
      }
    }
}

// ---------------------------------------------------------------------------
// Kernel 2: h2 = relu(h1 @ W2^T + b2) (W2 cast in-kernel), kept in LDS;
// then logits = h2 @ W3^T + b3 and log_softmax. BM=32, BN=128 (full N),
// K=256 in 4 double-buffered steps; 256 blocks.
// ---------------------------------------------------------------------------
__global__ __launch_bounds__(256) void gemm2_head(
    const ushort* __restrict__ h1, const float* __restrict__ W2,
    const float* __restrict__ b2, const float* __restrict__ W3,
    const float* __restrict__ b3, float* __restrict__ out) {
  constexpr int LDA = 72;
  constexpr int NK = 4;   // K = 256, BK = 64
  __shared__ ushort As[2][32 * LDA];
  __shared__ ushort Bs[2][128 * LDA];
  __shared__ float h2f[32][132];
  __shared__ float W3s[1280];

  const int tid = threadIdx.x;
  const int lane = tid & 63;
  const int w = tid >> 6, wm = w >> 1, wn = w & 1;
  const int m0 = blockIdx.x * 32;

  for (int i = tid; i < 1280; i += 256) W3s[i] = W3[i];

  const int ar = tid >> 3, asl = tid & 7;          // A: 32 rows x 8 slots
  const int br = tid >> 4, kc4 = (tid & 15) * 4;   // B: rows c*16+br

  uint4 av;
  float4 bw[8];

  auto loadT = [&](int kt) {
    const int k0 = kt * 64;
    av = *(const uint4*)(h1 + (size_t)(m0 + ar) * 256 + k0 + asl * 8);
#pragma unroll
    for (int c = 0; c < 8; ++c)
      bw[c] = *(const float4*)(W2 + (size_t)(c * 16 + br) * 256 + k0 + kc4);
  };
  auto writeT = [&](int buf) {
    *(uint4*)(As[buf] + ar * LDA + asl * 8) = av;
#pragma unroll
    for (int c = 0; c < 8; ++c)
      *(ushort4*)(Bs[buf] + (c * 16 + br) * LDA + kc4) =
          pack4(bw[c].x, bw[c].y, bw[c].z, bw[c].w);
  };

  f32x4 acc[4];
#pragma unroll
  for (int n = 0; n < 4; ++n) {
    f32x4 z = {0.f, 0.f, 0.f, 0.f};
    acc[n] = z;
  }

  auto mma = [&](int buf) {
    const ushort* as = As[buf];
    const ushort* bs = Bs[buf];
#pragma unroll
    for (int ks = 0; ks < 2; ++ks) {
      int r = wm * 16 + (lane & 15);
      short8 af = *(const short8*)(as + r * LDA + ks * 32 + (lane >> 4) * 8);
#pragma unroll
      for (int n = 0; n < 4; ++n) {
        int cdx = wn * 64 + n * 16 + (lane & 15);
        short8 bf = *(const short8*)(bs + cdx * LDA + ks * 32 + (lane >> 4) * 8);
        acc[n] = __builtin_amdgcn_mfma_f32_16x16x32_bf16(af, bf, acc[n], 0, 0, 0);
      }
    }
  };

  loadT(0);
  writeT(0);
  __syncthreads();
  int cur = 0;
  for (int kt = 0; kt < NK; ++kt) {
    if (kt + 1 < NK) loadT(kt + 1);
    mma(cur);
    if (kt + 1 < NK) writeT(cur ^ 1);
    __syncthreads();
    cur ^= 1;
  }

  // h2 tile -> LDS with bias + relu
#pragma unroll
  for (int n = 0; n < 4; ++n) {
    int col = wn * 64 + n * 16 + (lane & 15);
    float bval = b2[col];
#pragma unroll
    for (int r = 0; r < 4; ++r)
      h2f[wm * 16 + (lane >> 4) * 4 + r][col] = fmaxf(acc[n][r] + bval, 0.f);
  }
  __syncthreads();

  // head: row r = tid>>3 (32 rows), partial p = tid&7 over k = e*8+p
  {
    int r = tid >> 3, p = tid & 7;
    float a10[10];
#pragma unroll
    for (int n = 0; n < 10; ++n) a10[n] = 0.f;
#pragma unroll
    for (int e = 0; e < 16; ++e) {
      int k = e * 8 + p;
      float hv = h2f[r][k];
#pragma unroll
      for (int n = 0; n < 10; ++n) a10[n] = fmaf(hv, W3s[n * 128 + k], a10[n]);
    }
#pragma unroll
    for (int n = 0; n < 10; ++n) {
      a10[n] += __shfl_xor(a10[n], 1);
      a10[n] += __shfl_xor(a10[n], 2);
      a10[n] += __shfl_xor(a10[n], 4);
    }
    if (p == 0) {
#pragma unroll
      for (int n = 0; n < 10; ++n) a10[n] += b3[n];
      float mx = a10[0];
#pragma unroll
      for (int n = 1; n < 10; ++n) mx = fmaxf(mx, a10[n]);
      float s = 0.f;
#pragma unroll
      for (int n = 0; n < 10; ++n) s += __expf(a10[n] - mx);
      float lse = mx + __logf(s);
      float* po = out + (size_t)(m0 + r) * 10;
#pragma unroll
      for (int n = 0; n < 10; ++n) po[n] = a10[n] - lse;
    }
  }
}

// ---------------------------------------------------------------------------
extern "C" void kernel_launch(void* const* d_in, const int* in_sizes, int n_in,
                              void* d_out, int out_size, void* d_ws, size_t ws_size,
                              hipStream_t stream) {
  const float* x  = (const float*)d_in[0];   // (8192,1,28,28)
  // d_in[1] = params: provably unused (diagonal phases cancel in |amp|^2)
  const float* W1 = (const float*)d_in[2];
  const float* b1 = (const float*)d_in[3];
  const float* W2 = (const float*)d_in[4];
  const float* b2 = (const float*)d_in[5];
  const float* W3 = (const float*)d_in[6];
  const float* b3 = (const float*)d_in[7];
  float* out = (float*)d_out;

  ushort* h1 = (ushort*)d_ws;                 // 8192 x 256 bf16 (4.2 MB)

  hipLaunchKernelGGL(gemm1_fused, dim3(512), dim3(256), 0, stream, x, W1, b1, h1);
  hipLaunchKernelGGL(gemm2_head, dim3(256), dim3(256), 0, stream, h1, W2, b2, W3, b3, out);
}